// Round 6
// baseline (431.120 us; speedup 1.0000x reference)
//
#include <hip/hip_runtime.h>
#include <stdint.h>

// Problem constants (fixed by reference)
#define T_TOK 32768   // B*S = 8*4096
#define DIN   256
#define DHID  512
#define DOUT  256
#define NEXP  64
#define TM    64      // tokens per expert-FFN tile
#define FFN_BLOCKS 1280                    // 8 XCD groups x 160 slots
#define GSLOT (FFN_BLOCKS / 8)
#define ROUTER_BLOCKS (T_TOK / 64)         // 512
#define PREP_BLOCKS   8192
#define OUTZ_BLOCKS   512                  // zero d_out (8.39M floats)

typedef __attribute__((ext_vector_type(8))) short short8;   // 8 bf16 (4 VGPRs)
typedef __attribute__((ext_vector_type(4))) float f32x4;

// ---- workspace layout (bytes) ----  total ~34.6 MB
#define OFF_W1F   0u                       // 16 MiB bf16 fragment-ordered W1
#define OFF_W2F   16777216u                // 16 MiB bf16 fragment-ordered W2
#define OFF_BASE  33554432u
#define OFF_CNT   (OFF_BASE + 0u)          // 64 int
#define OFF_CUR   (OFF_BASE + 256u)        // 64 int
#define OFF_OFFS  (OFF_BASE + 512u)        // 65 int (token-slot prefix)
#define OFF_GOFF  (OFF_BASE + 1024u)       // 8 groups x 9 int (per-XCD tile prefix)
#define OFF_TOPKE (OFF_BASE + 2048u)       // 2T int
#define OFF_TOPKG (OFF_TOPKE + 262144u)    // 2T float
#define OFF_PERM  (OFF_TOPKG + 262144u)    // 2T int
#define OFF_PGATE (OFF_PERM + 262144u)     // 2T float

__device__ __forceinline__ unsigned short f2bf(float f) {
    union { float f; unsigned u; } a; a.f = f;
    unsigned u = a.u;
    u += 0x7fffu + ((u >> 16) & 1u);   // RNE
    return (unsigned short)(u >> 16);
}
__device__ __forceinline__ unsigned pack2(float a, float b) {
    return (unsigned)f2bf(a) | ((unsigned)f2bf(b) << 16);
}

// ---------------------------------------------------------------------------
// Fused K1: blocks [0,512) = router; [512, 8704) = weight prep (fp32 -> bf16
// MFMA B-fragment order); [8704, 9216) = zero d_out (replaces a memset node).
// B-fragment order: per 16(N)x32(K) tile, lane l holds
// B[k=kt*32+(l>>4)*8+j][n=nt*16+(l&15)], 64 lanes * 16B contiguous.
__global__ __launch_bounds__(256) void router_prep(const float* __restrict__ x,
                                                   const float* __restrict__ Wr,
                                                   const float* __restrict__ br,
                                                   const float* __restrict__ W1,
                                                   const float* __restrict__ W2,
                                                   uint4* __restrict__ W1f,
                                                   uint4* __restrict__ W2f,
                                                   int* __restrict__ topk_e,
                                                   float* __restrict__ topk_g,
                                                   int* __restrict__ cnt,
                                                   float4* __restrict__ outz) {
    __shared__ float xl[64][68];   // x chunk [tok][d], later logits [tok][e]
    __shared__ float wt[64][68];   // Wr transposed chunk [e][d]
    __shared__ int lcnt[NEXP];
    int tid = threadIdx.x;

    if (blockIdx.x >= ROUTER_BLOCKS + PREP_BLOCKS) {
        // ---------------- zero d_out ----------------
        int base = (blockIdx.x - (ROUTER_BLOCKS + PREP_BLOCKS)) * 256 + tid;
        float4 z = {0.0f, 0.0f, 0.0f, 0.0f};
#pragma unroll
        for (int i = 0; i < 16; ++i) outz[base + i * (OUTZ_BLOCKS * 256)] = z;
        return;
    }
    if (blockIdx.x >= ROUTER_BLOCKS) {
        // ---------------- weight prep ----------------
        int g = (blockIdx.x - ROUTER_BLOCKS) * 256 + tid;   // 0 .. 2*2^20-1
        int isW2 = g >> 20;
        int gg = g & ((1 << 20) - 1);
        int l = gg & 63;
        int t = gg >> 6;            // tile id over all experts
        int e = t >> 8;
        int rem = t & 255;
        int quad = l >> 4, lr = l & 15;
        float v[8];
        if (!isW2) {
            int nt = rem >> 3, kt = rem & 7;          // 32 n-tiles, 8 k-tiles
            int kb = kt * 32 + quad * 8;
            int n = nt * 16 + lr;
            const float* s = W1 + (size_t)e * DIN * DHID + n;
#pragma unroll
            for (int j = 0; j < 8; ++j) v[j] = s[(size_t)(kb + j) * DHID];
        } else {
            int nt = rem >> 4, kt = rem & 15;         // 16 n-tiles, 16 k-tiles
            int kb = kt * 32 + quad * 8;
            int n = nt * 16 + lr;
            const float* s = W2 + (size_t)e * DHID * DOUT + n;
#pragma unroll
            for (int j = 0; j < 8; ++j) v[j] = s[(size_t)(kb + j) * DOUT];
        }
        uint4 o;
        o.x = pack2(v[0], v[1]); o.y = pack2(v[2], v[3]);
        o.z = pack2(v[4], v[5]); o.w = pack2(v[6], v[7]);
        (isW2 ? W2f : W1f)[gg] = o;
        return;
    }

    // ---------------- router (fp32 logits; bf16 would swap near-tie picks) --
    if (tid < NEXP) lcnt[tid] = 0;
    int a = tid >> 4;        // expert group base
    int bcol = tid & 15;     // token group base
    int tok0 = blockIdx.x * 64;
    float c[4][4];
#pragma unroll
    for (int i = 0; i < 4; ++i)
#pragma unroll
        for (int j = 0; j < 4; ++j) c[i][j] = 0.0f;

    for (int chunk = 0; chunk < 4; ++chunk) {
        int d0 = chunk * 64;
        {   // stage x[tok0..tok0+63][d0..d0+63]
            int tok = tid >> 2, off = (tid & 3) * 16;
            const float4* s = (const float4*)(x + (size_t)(tok0 + tok) * DIN + d0 + off);
            float4* d = (float4*)&xl[tok][off];
#pragma unroll
            for (int i = 0; i < 4; ++i) d[i] = s[i];
        }
        {   // stage Wr chunk transposed: wt[e][dd] = Wr[d0+dd][e]
            int dd = tid >> 2, ecol = (tid & 3) * 16;
            const float* s = Wr + (size_t)(d0 + dd) * NEXP + ecol;
#pragma unroll
            for (int j = 0; j < 16; ++j) wt[ecol + j][dd] = s[j];
        }
        __syncthreads();
#pragma unroll 4
        for (int d = 0; d < 64; d += 4) {
            float4 xv[4], wv[4];
#pragma unroll
            for (int i = 0; i < 4; ++i) xv[i] = *(const float4*)&xl[bcol + i * 16][d];
#pragma unroll
            for (int j = 0; j < 4; ++j) wv[j] = *(const float4*)&wt[a + j * 16][d];
#pragma unroll
            for (int i = 0; i < 4; ++i)
#pragma unroll
                for (int j = 0; j < 4; ++j) {
                    c[i][j] = fmaf(xv[i].x, wv[j].x, c[i][j]);
                    c[i][j] = fmaf(xv[i].y, wv[j].y, c[i][j]);
                    c[i][j] = fmaf(xv[i].z, wv[j].z, c[i][j]);
                    c[i][j] = fmaf(xv[i].w, wv[j].w, c[i][j]);
                }
        }
        __syncthreads();
    }
#pragma unroll
    for (int i = 0; i < 4; ++i)
#pragma unroll
        for (int j = 0; j < 4; ++j)
            xl[bcol + i * 16][a + j * 16] = c[i][j] + br[a + j * 16];
    __syncthreads();

    int w = tid >> 6, lane = tid & 63;
    for (int ti = 0; ti < 16; ++ti) {
        int tl = w * 16 + ti;
        float acc = xl[tl][lane];     // lane == expert
        float v = acc; int idx = lane;
#pragma unroll
        for (int m = 32; m; m >>= 1) {
            float ov = __shfl_xor(v, m); int oi = __shfl_xor(idx, m);
            if (ov > v || (ov == v && oi < idx)) { v = ov; idx = oi; }
        }
        int e0 = idx; float l0 = v;
        float v2 = (lane == e0) ? -3.4e38f : acc; int idx2 = lane;
#pragma unroll
        for (int m = 32; m; m >>= 1) {
            float ov = __shfl_xor(v2, m); int oi = __shfl_xor(idx2, m);
            if (ov > v2 || (ov == v2 && oi < idx2)) { v2 = ov; idx2 = oi; }
        }
        if (lane == 0) {
            int t = tok0 + tl;
            float ex = expf(v2 - l0);         // <= 1
            float g1 = ex / (1.0f + ex);
            topk_e[2 * t] = e0; topk_e[2 * t + 1] = idx2;
            topk_g[2 * t] = 1.0f - g1; topk_g[2 * t + 1] = g1;
            atomicAdd(&lcnt[e0], 1);
            atomicAdd(&lcnt[idx2], 1);
        }
    }
    __syncthreads();
    if (tid < NEXP) atomicAdd(&cnt[tid], lcnt[tid]);
}

// ---------------------------------------------------------------------------
// K2: scatter; wave 0 also scans cnt. Block 0 publishes offs (token-slot
// prefix) and gOffs (per-XCD-group tile prefix over that group's 8 experts).
__global__ __launch_bounds__(256) void scatter_kernel(const int* __restrict__ topk_e,
                                                      const float* __restrict__ topk_g,
                                                      const int* __restrict__ cnt,
                                                      int* __restrict__ cursor,
                                                      int* __restrict__ perm,
                                                      float* __restrict__ pgate,
                                                      int* __restrict__ offs_g,
                                                      int* __restrict__ gOffs_g) {
    __shared__ int lcnt[NEXP], lbase[NEXP], sOffs[NEXP];
    int tid = threadIdx.x;
    if (tid < NEXP) lcnt[tid] = 0;
    if (tid < 64) {   // wave 0
        int c = cnt[tid];
        int ic = c;
#pragma unroll
        for (int d = 1; d < 64; d <<= 1) {
            int vc = __shfl_up(ic, d);
            if (tid >= d) ic += vc;
        }
        sOffs[tid] = ic - c;
        if (blockIdx.x == 0) {
            offs_g[tid] = ic - c;
            if (tid == 63) offs_g[64] = ic;
            // per-XCD-group tile prefix: experts e = q + 8j for group q
            int tiles = (c + TM - 1) / TM;
            int q = tid & 7, j = tid >> 3;
            int pre = 0, tot = 0;
            for (int jj = 0; jj < 8; ++jj) {
                int v = __shfl(tiles, q + 8 * jj);
                tot += v;
                if (jj < j) pre += v;
            }
            gOffs_g[q * 9 + j] = pre;
            if (j == 7) gOffs_g[q * 9 + 8] = tot;
        }
    }
    __syncthreads();
    int t = blockIdx.x * 256 + tid;
    int e0 = topk_e[2 * t], e1 = topk_e[2 * t + 1];
    int i0 = atomicAdd(&lcnt[e0], 1);
    int i1 = atomicAdd(&lcnt[e1], 1);
    __syncthreads();
    if (tid < NEXP) lbase[tid] = atomicAdd(&cursor[tid], lcnt[tid]);
    __syncthreads();
    int p0 = sOffs[e0] + lbase[e0] + i0;
    int p1 = sOffs[e1] + lbase[e1] + i1;
    perm[p0] = t; pgate[p0] = topk_g[2 * t];
    perm[p1] = t; pgate[p1] = topk_g[2 * t + 1];
}

// ---------------------------------------------------------------------------
// Expert FFN v6: TM=64, XCD-affinity grid (group q=bid&7). 4 waves.
// m97-style register blocking: wave holds ALL 4 m-tiles; layer1 2 n-tiles
// (8 MFMA per 4 A-reads + 2 B-loads), layer2 4 n-tiles (16 MFMA per 4+4).
// B-fragments loaded straight global->VGPR (L2-resident via XCD affinity);
// fully-unrolled k-loops let the compiler software-pipeline with its own
// fine-grained vmcnt. Layer1->layer2 fused through 128-col H chunks in a
// double-buffered LDS tile (H never fully materialized): 1 barrier per chunk,
// 4 per tile. LDS ~72 KB -> 2 blocks/CU.
// MFMA 16x16x32 bf16 layouts: A[m=lane&15][k=(lane>>4)*8+j];
// C/D col=lane&15, row=(lane>>4)*4+reg.
__global__ __launch_bounds__(256, 2) void expert_ffn(const float* __restrict__ x,
                                                     const uint4* __restrict__ W1f,
                                                     const uint4* __restrict__ W2f,
                                                     const float* __restrict__ b1,
                                                     const float* __restrict__ b2,
                                                     const int* __restrict__ cnt,
                                                     const int* __restrict__ offs,
                                                     const int* __restrict__ gOffs,
                                                     const int* __restrict__ perm,
                                                     const float* __restrict__ pgate,
                                                     float* __restrict__ out) {
    __shared__ unsigned short xs[TM][DIN + 8];     // 33,792 B (stride 132 dw, +4 banks/row)
    __shared__ unsigned short Hb[2][TM][128 + 8];  // 34,816 B (stride 68 dw, +4 banks/row)
    __shared__ float bias1s[DHID];                 // 2 KB
    __shared__ float bias2s[DOUT];                 // 1 KB
    __shared__ int toks[TM];
    __shared__ float gs[TM];
    __shared__ int sOff[9];

    int tid = threadIdx.x;
    int q = blockIdx.x & 7, slot = blockIdx.x >> 3;
    if (tid < 9) sOff[tid] = gOffs[q * 9 + tid];
    __syncthreads();
    int L = sOff[8];
    int w = tid >> 6, lane = tid & 63, quad = lane >> 4, lr = lane & 15;

    for (int s = slot; s < L; s += GSLOT) {
        int j = 0;
#pragma unroll
        for (int jj = 1; jj < 8; ++jj) j += (sOff[jj] <= s) ? 1 : 0;
        int e = q + 8 * j;
        int ne = cnt[e];
        int tile0 = (s - sOff[j]) * TM;

        __syncthreads();   // prev iteration fully done with xs/toks/gs/bias
        if (tid < TM) {
            int idx = tile0 + tid;
            if (idx < ne) { int p = offs[e] + idx; toks[tid] = perm[p]; gs[tid] = pgate[p]; }
            else          { toks[tid] = 0; gs[tid] = 0.0f; }   // gate 0 -> no-op
        }
        if (tid < 128)
            *(float4*)&bias1s[tid * 4] = *(const float4*)(b1 + (size_t)e * DHID + tid * 4);
        else if (tid < 192)
            *(float4*)&bias2s[(tid - 128) * 4] = *(const float4*)(b2 + (size_t)e * DOUT + (tid - 128) * 4);
        __syncthreads();
        {   // gather x rows -> xs bf16; 4 threads per row
            int row = tid >> 2, c0 = (tid & 3) * 64;
            const float4* src = (const float4*)(x + (size_t)toks[row] * DIN + c0);
            unsigned* dst = (unsigned*)&xs[row][c0];
#pragma unroll
            for (int i = 0; i < 16; ++i) {
                float4 v = src[i];
                dst[2 * i]     = pack2(v.x, v.y);
                dst[2 * i + 1] = pack2(v.z, v.w);
            }
        }
        __syncthreads();

        const uint4* W1e = W1f + (size_t)e * 16384;
        const uint4* W2e = W2f + (size_t)e * 16384;
        f32x4 acc2[4][4];   // [n-tile][m-tile], persistent over kb
#pragma unroll
        for (int i = 0; i < 4; ++i)
#pragma unroll
            for (int mt = 0; mt < 4; ++mt) acc2[i][mt] = (f32x4){0.f, 0.f, 0.f, 0.f};

#pragma unroll
        for (int kb = 0; kb < 4; ++kb) {
            int buf = kb & 1;
            // ---- layer1 for H cols [kb*128, kb*128+128): wave w -> 2 n-tiles
            int nt0 = kb * 8 + w * 2;
            f32x4 acc1[2][4];
#pragma unroll
            for (int t2 = 0; t2 < 2; ++t2)
#pragma unroll
                for (int mt = 0; mt < 4; ++mt) acc1[t2][mt] = (f32x4){0.f, 0.f, 0.f, 0.f};
#pragma unroll
            for (int kc = 0; kc < 8; ++kc) {
                short8 a[4];
#pragma unroll
                for (int mt = 0; mt < 4; ++mt)
                    a[mt] = *(const short8*)&xs[mt * 16 + lr][kc * 32 + quad * 8];
                uint4 b0 = W1e[(size_t)nt0 * 512 + kc * 64 + lane];
                uint4 b1r = W1e[(size_t)(nt0 + 1) * 512 + kc * 64 + lane];
                short8 bb0 = __builtin_bit_cast(short8, b0);
                short8 bb1 = __builtin_bit_cast(short8, b1r);
#pragma unroll
                for (int mt = 0; mt < 4; ++mt) {
                    acc1[0][mt] = __builtin_amdgcn_mfma_f32_16x16x32_bf16(a[mt], bb0, acc1[0][mt], 0, 0, 0);
                    acc1[1][mt] = __builtin_amdgcn_mfma_f32_16x16x32_bf16(a[mt], bb1, acc1[1][mt], 0, 0, 0);
                }
            }
#pragma unroll
            for (int t2 = 0; t2 < 2; ++t2) {
                float bias = bias1s[(nt0 + t2) * 16 + lr];
                int cl = (w * 2 + t2) * 16 + lr;
#pragma unroll
                for (int mt = 0; mt < 4; ++mt)
#pragma unroll
                    for (int r = 0; r < 4; ++r)
                        Hb[buf][mt * 16 + quad * 4 + r][cl] =
                            f2bf(fmaxf(acc1[t2][mt][r] + bias, 0.0f));
            }
            __syncthreads();   // H chunk kb ready (also fences prev buf reuse)

            // ---- layer2 partial: K rows [kb*128, kb*128+128), wave w -> 4 n-tiles
#pragma unroll
            for (int kc = 0; kc < 4; ++kc) {
                short8 a[4];
#pragma unroll
                for (int mt = 0; mt < 4; ++mt)
                    a[mt] = *(const short8*)&Hb[buf][mt * 16 + lr][kc * 32 + quad * 8];
#pragma unroll
                for (int i = 0; i < 4; ++i) {
                    int ng = w * 4 + i;
                    uint4 braw = W2e[(size_t)ng * 1024 + (size_t)(kb * 4 + kc) * 64 + lane];
                    short8 b = __builtin_bit_cast(short8, braw);
#pragma unroll
                    for (int mt = 0; mt < 4; ++mt)
                        acc2[i][mt] = __builtin_amdgcn_mfma_f32_16x16x32_bf16(a[mt], b, acc2[i][mt], 0, 0, 0);
                }
            }
            // no barrier here: next kb's layer1 writes buf^1; the barrier above
            // (next kb) orders all waves' layer2(kb) reads before buf reuse.
        }

        // ---- deferred epilogue: out[tok] += gate * (y + b2) ----
#pragma unroll
        for (int i = 0; i < 4; ++i) {
            int n = (w * 4 + i) * 16;
            float bias = bias2s[n + lr];
#pragma unroll
            for (int mt = 0; mt < 4; ++mt)
#pragma unroll
                for (int r = 0; r < 4; ++r) {
                    int m = mt * 16 + quad * 4 + r;
                    atomicAdd(&out[(size_t)toks[m] * DOUT + n + lr],
                              gs[m] * (acc2[i][mt][r] + bias));
                }
        }
    }
}

// ---------------------------------------------------------------------------
extern "C" void kernel_launch(void* const* d_in, const int* in_sizes, int n_in,
                              void* d_out, int out_size, void* d_ws, size_t ws_size,
                              hipStream_t stream) {
    (void)in_sizes; (void)n_in; (void)ws_size; (void)out_size;   // ws >= ~34.6 MB
    const float* x  = (const float*)d_in[0];
    const float* Wr = (const float*)d_in[1];
    const float* br = (const float*)d_in[2];
    const float* W1 = (const float*)d_in[3];
    const float* b1 = (const float*)d_in[4];
    const float* W2 = (const float*)d_in[5];
    const float* b2 = (const float*)d_in[6];
    float* out = (float*)d_out;
    char* ws = (char*)d_ws;

    uint4* W1f    = (uint4*)(ws + OFF_W1F);
    uint4* W2f    = (uint4*)(ws + OFF_W2F);
    int*   cnt    = (int*)(ws + OFF_CNT);
    int*   cursor = (int*)(ws + OFF_CUR);
    int*   offs   = (int*)(ws + OFF_OFFS);
    int*   gOffs  = (int*)(ws + OFF_GOFF);
    int*   topk_e = (int*)(ws + OFF_TOPKE);
    float* topk_g = (float*)(ws + OFF_TOPKG);
    int*   perm   = (int*)(ws + OFF_PERM);
    float* pgate  = (float*)(ws + OFF_PGATE);

    hipMemsetAsync(ws + OFF_CNT, 0, 512, stream);   // cnt + cursor

    router_prep<<<ROUTER_BLOCKS + PREP_BLOCKS + OUTZ_BLOCKS, 256, 0, stream>>>(
        x, Wr, br, W1, W2, W1f, W2f, topk_e, topk_g, cnt, (float4*)out);
    scatter_kernel<<<T_TOK / 256, 256, 0, stream>>>(topk_e, topk_g, cnt, cursor,
                                                    perm, pgate, offs, gOffs);
    expert_ffn<<<FFN_BLOCKS, 256, 0, stream>>>(x, W1f, W2f, b1, b2, cnt, offs, gOffs,
                                               perm, pgate, out);
}